// Round 8
// baseline (2199.837 us; speedup 1.0000x reference)
//
#include <hip/hip_runtime.h>

// Problem constants: N=512, BS=64, DIM=256, SIZE=8192
#define T_TOTAL 32768   // N*BS queries
#define D       256
#define K       8192
#define BQ      64      // queries per block tile (4 row-tiles of 16) — all waves share
#define KSPLIT  4
#define KSLICE  (K / KSPLIT)
#define NSLICE  (KSPLIT * 4)        // 4 wn-quadrants write disjoint partial slices
#define NCT     (K / 16)            // 512 code-tiles
#define KT_STRIDE (NCT * 64 * 8)    // halves per kt plane = 262144

typedef _Float16 half4f  __attribute__((ext_vector_type(4)));
typedef _Float16 half8f  __attribute__((ext_vector_type(8)));
typedef float    floatx4 __attribute__((ext_vector_type(4)));

// d_out scratch layout (floats): [0, 1048576) partial (16 slices x T x float2),
// then Bhi (1048576 f), then Blo (1048576 f). All consumed before gather overwrites.
#define PARTIAL_F 1048576
#define BHALVES   2097152   // halves per B array (8*512*64*8)

// ---------------- kernel 1: half squared norms of vocab rows (fp32 exact) ----------------
__global__ void hv2_kernel(const float* __restrict__ vocab, float* __restrict__ hv2) {
    int code = blockIdx.x * 4 + (threadIdx.x >> 6);
    int lane = threadIdx.x & 63;
    const float4* row = (const float4*)(vocab + (size_t)code * D);
    float4 v = row[lane];
    float s = v.x * v.x + v.y * v.y + v.z * v.z + v.w * v.w;
    #pragma unroll
    for (int off = 32; off; off >>= 1) s += __shfl_down(s, off, 64);
    if (lane == 0) hv2[code] = 0.5f * s;
}

__device__ __forceinline__ _Float16 hi16(float x) { return (_Float16)x; }
__device__ __forceinline__ _Float16 lo16(float x, _Float16 h) { return (_Float16)(x - (float)h); }
__device__ __forceinline__ void split4(float4 v, half4f& h, half4f& l) {
    _Float16 hx = hi16(v.x), hy = hi16(v.y), hz = hi16(v.z), hw = hi16(v.w);
    h = (half4f){hx, hy, hz, hw};
    l = (half4f){lo16(v.x, hx), lo16(v.y, hy), lo16(v.z, hz), lo16(v.w, hw)};
}

// ------- kernel 1b: split vocab into fp16 hi/lo, fragment-order global layout -------
// tile(kt 0..7, ct 0..511): 64 lanes x 8 halves; element (code c, dim k) ->
// kt=k>>5, ct=c>>4, lane=(c&15)+16*((k&31)>>3), j=k&7. Addr=((kt*512+ct)*64+lane)*8+j.
__global__ void bsplit_kernel(const float* __restrict__ vocab,
                              _Float16* __restrict__ bhi, _Float16* __restrict__ blo) {
    const int ct = blockIdx.x;           // 512 blocks, one 16-code tile each
    const int t  = threadIdx.x;
    const int k4 = t & 63;               // float4 index along D
    const float4* voc4 = (const float4*)vocab;
    const int kt = k4 >> 3, kg = (k4 >> 1) & 3, h = k4 & 1;
    #pragma unroll
    for (int ci = 0; ci < 4; ++ci) {
        int cc = (t >> 6) * 4 + ci;      // code within tile
        float4 v = voc4[(size_t)(ct * 16 + cc) * (D / 4) + k4];
        half4f hh, ll;
        split4(v, hh, ll);
        size_t off = (((size_t)kt * NCT + ct) * 64 + (cc + 16 * kg)) * 8 + h * 4;
        *(half4f*)&bhi[off] = hh;
        *(half4f*)&blo[off] = ll;
    }
}

// -------- kernel 2: MFMA argmin, barrier-free K-loop, 64q x 64c per wave --------
// block 256 = 4 waves; wave wn in 0..3 covers code quadrant; all waves share 64 A rows.
// grid (T/BQ, KSPLIT). Wave writes partial slice (blockIdx.y*4 + wn) -> 16 disjoint slices.
__launch_bounds__(256, 2)
__global__ void argmin_kernel(const float* __restrict__ seq,
                              const _Float16* __restrict__ bhi,
                              const _Float16* __restrict__ blo,
                              const float* __restrict__ hv2,
                              float2* __restrict__ partial) {
    // A LDS in fragment order [rt 0..3][kt 0..7][flane 0..63][8], XOR-swizzled by kt<<3
    __shared__ _Float16 AhL[4 * 8 * 64 * 8];   // 32 KB
    __shared__ _Float16 AlL[4 * 8 * 64 * 8];   // 32 KB

    const int t    = threadIdx.x;
    const int lane = t & 63;
    const int wn   = t >> 6;            // code quadrant 0..3
    const int q0   = blockIdx.x * BQ;
    const int k0   = blockIdx.y * KSLICE;

    const float4* seq4 = (const float4*)seq;

    // ---- prologue: split A (64 rows x 256 dims) into fragment-order LDS, once ----
    #pragma unroll
    for (int i = 0; i < 16; ++i) {
        int f   = t + 256 * i;          // 0..4095 float4s
        int row = f >> 6;               // 0..63
        int d4  = f & 63;               // float4 along D
        float4 v = seq4[(size_t)(q0 + row) * (D / 4) + d4];
        half4f h, l;
        split4(v, h, l);
        int kt = d4 >> 3, kg = (d4 >> 1) & 3, hh = d4 & 1;
        int off = (((((row >> 4) * 8 + kt) * 64) + ((row & 15) + 16 * kg)) * 8 + hh * 4)
                  ^ (kt << 3);          // swizzle: spreads write banks 32-way -> 4-way
        *(half4f*)&AhL[off] = h;
        *(half4f*)&AlL[off] = l;
    }
    __syncthreads();   // the ONLY barrier

    float best[16];
    int   bidx[16];
    #pragma unroll
    for (int b = 0; b < 16; ++b) { best[b] = 3.4e38f; bidx[b] = 0; }

    const _Float16* bh_l = bhi + (size_t)lane * 8;
    const _Float16* bl_l = blo + (size_t)lane * 8;

    for (int c0i = 0; c0i < KSLICE / 256; ++c0i) {   // 8 c0 tiles of 256 codes
        const int c0  = k0 + c0i * 256;
        const int ct0 = (c0 >> 4) + wn * 4;          // this wave's 4 code-tiles

        floatx4 acc[4][4];
        #pragma unroll
        for (int mi = 0; mi < 4; ++mi)
            #pragma unroll
            for (int nj = 0; nj < 4; ++nj) acc[mi][nj] = (floatx4){0.f, 0.f, 0.f, 0.f};

        // register double-buffer on B fragments
        half8f bhb[2][4], blb[2][4];
        {
            const size_t kb = (size_t)ct0 * 512;
            #pragma unroll
            for (int nj = 0; nj < 4; ++nj) {
                bhb[0][nj] = *(const half8f*)&bh_l[kb + nj * 512];
                blb[0][nj] = *(const half8f*)&bl_l[kb + nj * 512];
            }
        }

        #pragma unroll
        for (int kt = 0; kt < 8; ++kt) {
            const int cur = kt & 1, nxt = cur ^ 1;
            if (kt < 7) {   // prefetch next kt's B while MFMAing this one
                const size_t kb = (size_t)(kt + 1) * KT_STRIDE + (size_t)ct0 * 512;
                #pragma unroll
                for (int nj = 0; nj < 4; ++nj) {
                    bhb[nxt][nj] = *(const half8f*)&bh_l[kb + nj * 512];
                    blb[nxt][nj] = *(const half8f*)&bl_l[kb + nj * 512];
                }
            }
            // A fragments from LDS ((lane^kt)*16B permutation: conflict-free b128)
            half8f ah[4], al[4];
            #pragma unroll
            for (int mi = 0; mi < 4; ++mi) {
                const int ao = (((mi * 8 + kt) * 64 + lane) * 8) ^ (kt << 3);
                ah[mi] = *(const half8f*)&AhL[ao];
                al[mi] = *(const half8f*)&AlL[ao];
            }
            #pragma unroll
            for (int mi = 0; mi < 4; ++mi)
                #pragma unroll
                for (int nj = 0; nj < 4; ++nj) {
                    floatx4 a = acc[mi][nj];
                    a = __builtin_amdgcn_mfma_f32_16x16x32_f16(al[mi], blb[cur][nj], a, 0, 0, 0);
                    a = __builtin_amdgcn_mfma_f32_16x16x32_f16(al[mi], bhb[cur][nj], a, 0, 0, 0);
                    a = __builtin_amdgcn_mfma_f32_16x16x32_f16(ah[mi], blb[cur][nj], a, 0, 0, 0);
                    a = __builtin_amdgcn_mfma_f32_16x16x32_f16(ah[mi], bhb[cur][nj], a, 0, 0, 0);
                    acc[mi][nj] = a;
                }
        }

        // epilogue: s = 0.5*|v|^2 - dot; running first-argmin (ascending c per lane).
        // C/D layout: col = lane&15, row = (lane>>4)*4 + reg
        #pragma unroll
        for (int nj = 0; nj < 4; ++nj) {
            int c = c0 + (wn * 4 + nj) * 16 + (lane & 15);
            float hv = hv2[c];
            #pragma unroll
            for (int mi = 0; mi < 4; ++mi)
                #pragma unroll
                for (int r = 0; r < 4; ++r) {
                    float s = hv - acc[mi][nj][r];
                    int b = mi * 4 + r;
                    if (s < best[b]) { best[b] = s; bidx[b] = c; }
                }
        }
    }

    // reduce across the 16 col-lanes (same rows, 16 different cols)
    #pragma unroll
    for (int off = 1; off < 16; off <<= 1) {
        #pragma unroll
        for (int b = 0; b < 16; ++b) {
            float ob = __shfl_xor(best[b], off, 64);
            int   oi = __shfl_xor(bidx[b], off, 64);
            if (ob < best[b] || (ob == best[b] && oi < bidx[b])) {
                best[b] = ob; bidx[b] = oi;
            }
        }
    }
    if ((lane & 15) == 0) {
        const size_t sl = (size_t)(blockIdx.y * 4 + wn) * T_TOTAL;  // disjoint per wn
        #pragma unroll
        for (int mi = 0; mi < 4; ++mi)
            #pragma unroll
            for (int r = 0; r < 4; ++r) {
                int q = q0 + mi * 16 + (lane >> 4) * 4 + r;
                partial[sl + q] = make_float2(best[mi * 4 + r], (float)bidx[mi * 4 + r]);
            }
    }
}

// ------- kernel 3: fold 16 partial slices (value min, tie -> smaller global index) -------
__global__ void reduce_kernel(const float2* __restrict__ partial, int* __restrict__ idx) {
    int q = blockIdx.x * 256 + threadIdx.x;
    float bm = 3.4e38f;
    int   bi = 0x7fffffff;
    #pragma unroll
    for (int s = 0; s < NSLICE; ++s) {
        float2 p = partial[(size_t)s * T_TOTAL + q];
        int pi = (int)p.y;
        if (p.x < bm || (p.x == bm && pi < bi)) { bm = p.x; bi = pi; }
    }
    idx[q] = bi;
}

// ---------------- kernel 4: gather vocab rows + emit indices as f32 ----------------
__global__ void gather_kernel(const float* __restrict__ vocab,
                              const int* __restrict__ idx,
                              float* __restrict__ out) {
    int r    = blockIdx.x * 4 + (threadIdx.x >> 6);  // one wave per output row
    int lane = threadIdx.x & 63;
    int k = idx[r];
    const float4* src = (const float4*)(vocab + (size_t)k * D);
    float4*       dst = (float4*)(out + (size_t)r * D);
    dst[lane] = src[lane];
    if (lane == 0) out[(size_t)T_TOTAL * D + r] = (float)k;
}

extern "C" void kernel_launch(void* const* d_in, const int* in_sizes, int n_in,
                              void* d_out, int out_size, void* d_ws, size_t ws_size,
                              hipStream_t stream) {
    const float* seq   = (const float*)d_in[0];   // [T, D] f32
    const float* vocab = (const float*)d_in[1];   // [K, D] f32
    float* out = (float*)d_out;

    float* hv2 = (float*)d_ws;                               // K floats
    int*   idx = (int*)((char*)d_ws + K * sizeof(float));    // T ints

    float2*   partial = (float2*)d_out;                      // 4 MB at head
    _Float16* bhi = (_Float16*)(out + PARTIAL_F);            // 4 MB
    _Float16* blo = bhi + BHALVES;                           // 4 MB
    // all scratch inside d_out's 33.7 MB quantized region; consumed before gather overwrites

    hipLaunchKernelGGL(hv2_kernel,    dim3(K / 4),                dim3(256), 0, stream, vocab, hv2);
    hipLaunchKernelGGL(bsplit_kernel, dim3(NCT),                  dim3(256), 0, stream, vocab, bhi, blo);
    hipLaunchKernelGGL(argmin_kernel, dim3(T_TOTAL / BQ, KSPLIT), dim3(256), 0, stream,
                       seq, bhi, blo, hv2, partial);
    hipLaunchKernelGGL(reduce_kernel, dim3(T_TOTAL / 256),        dim3(256), 0, stream, partial, idx);
    hipLaunchKernelGGL(gather_kernel, dim3(T_TOTAL / 4),          dim3(256), 0, stream, vocab, idx, out);
}

// Round 9
// 1982.046 us; speedup vs baseline: 1.1099x; 1.1099x over previous
//
#include <hip/hip_runtime.h>

// Problem constants: N=512, BS=64, DIM=256, SIZE=8192
#define T_TOTAL 32768   // N*BS queries
#define D       256
#define K       8192
#define BQ      64      // queries per block tile (4 row-tiles of 16) — shared by all 4 waves
#define KSPLIT  4
#define KSLICE  (K / KSPLIT)
#define NSLICE  (KSPLIT * 4)        // 4 wn-quadrants write disjoint partial slices
#define NCT     (K / 16)            // 512 code-tiles
#define KT_STRIDE (NCT * 64 * 8)    // halves per kt plane = 262144

typedef _Float16 half4f  __attribute__((ext_vector_type(4)));
typedef _Float16 half8f  __attribute__((ext_vector_type(8)));
typedef float    floatx4 __attribute__((ext_vector_type(4)));

// d_out scratch layout (floats): [0, 1048576) partial (16 slices x T x float2),
// then Bhi (1048576 f), then Blo (1048576 f). All consumed before gather overwrites.
#define PARTIAL_F 1048576
#define BHALVES   2097152   // halves per B array (8*512*64*8)

// ---------------- kernel 1: half squared norms of vocab rows (fp32 exact) ----------------
__global__ void hv2_kernel(const float* __restrict__ vocab, float* __restrict__ hv2) {
    int code = blockIdx.x * 4 + (threadIdx.x >> 6);
    int lane = threadIdx.x & 63;
    const float4* row = (const float4*)(vocab + (size_t)code * D);
    float4 v = row[lane];
    float s = v.x * v.x + v.y * v.y + v.z * v.z + v.w * v.w;
    #pragma unroll
    for (int off = 32; off; off >>= 1) s += __shfl_down(s, off, 64);
    if (lane == 0) hv2[code] = 0.5f * s;
}

__device__ __forceinline__ _Float16 hi16(float x) { return (_Float16)x; }
__device__ __forceinline__ _Float16 lo16(float x, _Float16 h) { return (_Float16)(x - (float)h); }
__device__ __forceinline__ void split4(float4 v, half4f& h, half4f& l) {
    _Float16 hx = hi16(v.x), hy = hi16(v.y), hz = hi16(v.z), hw = hi16(v.w);
    h = (half4f){hx, hy, hz, hw};
    l = (half4f){lo16(v.x, hx), lo16(v.y, hy), lo16(v.z, hz), lo16(v.w, hw)};
}

// ------- kernel 1b: split vocab into fp16 hi/lo, fragment-order global layout -------
// tile(kt 0..7, ct 0..511): 64 lanes x 8 halves; element (code c, dim k) ->
// kt=k>>5, ct=c>>4, lane=(c&15)+16*((k&31)>>3), j=k&7. Addr=((kt*512+ct)*64+lane)*8+j.
__global__ void bsplit_kernel(const float* __restrict__ vocab,
                              _Float16* __restrict__ bhi, _Float16* __restrict__ blo) {
    const int ct = blockIdx.x;           // 512 blocks, one 16-code tile each
    const int t  = threadIdx.x;
    const int k4 = t & 63;               // float4 index along D
    const float4* voc4 = (const float4*)vocab;
    const int kt = k4 >> 3, kg = (k4 >> 1) & 3, h = k4 & 1;
    #pragma unroll
    for (int ci = 0; ci < 4; ++ci) {
        int cc = (t >> 6) * 4 + ci;      // code within tile
        float4 v = voc4[(size_t)(ct * 16 + cc) * (D / 4) + k4];
        half4f hh, ll;
        split4(v, hh, ll);
        size_t off = (((size_t)kt * NCT + ct) * 64 + (cc + 16 * kg)) * 8 + h * 4;
        *(half4f*)&bhi[off] = hh;
        *(half4f*)&blo[off] = ll;
    }
}

// -------- kernel 2: MFMA argmin, barrier-free K-loop, 64q x 64c per wave --------
// block 256 = 4 waves; wave wn 0..3 covers a code quadrant; all waves share 64 A rows.
// grid (T/BQ, KSPLIT). Wave writes partial slice (blockIdx.y*4 + wn) -> 16 disjoint slices.
// NOTE: NO register double-buffer on B (R8 spilled: 4.7 GB scratch writes at +64 live regs).
__launch_bounds__(256, 2)
__global__ void argmin_kernel(const float* __restrict__ seq,
                              const _Float16* __restrict__ bhi,
                              const _Float16* __restrict__ blo,
                              const float* __restrict__ hv2,
                              float2* __restrict__ partial) {
    // A LDS in fragment order [rt 0..3][kt 0..7][flane 0..63][8], XOR-swizzled by kt<<3
    __shared__ _Float16 AhL[4 * 8 * 64 * 8];   // 32 KB
    __shared__ _Float16 AlL[4 * 8 * 64 * 8];   // 32 KB

    const int t    = threadIdx.x;
    const int lane = t & 63;
    const int wn   = t >> 6;            // code quadrant 0..3
    const int q0   = blockIdx.x * BQ;
    const int k0   = blockIdx.y * KSLICE;

    const float4* seq4 = (const float4*)seq;

    // ---- prologue: split A (64 rows x 256 dims) into fragment-order LDS, once ----
    #pragma unroll
    for (int i = 0; i < 16; ++i) {
        int f   = t + 256 * i;          // 0..4095 float4s
        int row = f >> 6;               // 0..63
        int d4  = f & 63;               // float4 along D
        float4 v = seq4[(size_t)(q0 + row) * (D / 4) + d4];
        half4f h, l;
        split4(v, h, l);
        int kt = d4 >> 3, kg = (d4 >> 1) & 3, hh = d4 & 1;
        int off = (((((row >> 4) * 8 + kt) * 64) + ((row & 15) + 16 * kg)) * 8 + hh * 4)
                  ^ (kt << 3);          // swizzle: write conflicts 32-way -> 4-way (R8-verified)
        *(half4f*)&AhL[off] = h;
        *(half4f*)&AlL[off] = l;
    }
    __syncthreads();   // the ONLY barrier

    float best[16];
    int   bidx[16];
    #pragma unroll
    for (int b = 0; b < 16; ++b) { best[b] = 3.4e38f; bidx[b] = 0; }

    const _Float16* bh_l = bhi + (size_t)lane * 8;
    const _Float16* bl_l = blo + (size_t)lane * 8;

    for (int c0i = 0; c0i < KSLICE / 256; ++c0i) {   // 8 c0 tiles of 256 codes
        const int c0  = k0 + c0i * 256;
        const int ct0 = (c0 >> 4) + wn * 4;          // this wave's 4 code-tiles

        floatx4 acc[4][4];
        #pragma unroll
        for (int mi = 0; mi < 4; ++mi)
            #pragma unroll
            for (int nj = 0; nj < 4; ++nj) acc[mi][nj] = (floatx4){0.f, 0.f, 0.f, 0.f};

        #pragma unroll
        for (int kt = 0; kt < 8; ++kt) {
            // A fragments from LDS ((lane^kt)*16B permutation: conflict-free b128)
            half8f ah[4], al[4];
            #pragma unroll
            for (int mi = 0; mi < 4; ++mi) {
                const int ao = (((mi * 8 + kt) * 64 + lane) * 8) ^ (kt << 3);
                ah[mi] = *(const half8f*)&AhL[ao];
                al[mi] = *(const half8f*)&AlL[ao];
            }
            const size_t kb = (size_t)kt * KT_STRIDE + (size_t)ct0 * 512;
            #pragma unroll
            for (int nj = 0; nj < 4; ++nj) {
                // B direct from global (coalesced b128, L2-resident); <=8 live B regs
                half8f bh = *(const half8f*)&bh_l[kb + nj * 512];
                half8f bl = *(const half8f*)&bl_l[kb + nj * 512];
                #pragma unroll
                for (int mi = 0; mi < 4; ++mi) {
                    floatx4 a = acc[mi][nj];
                    a = __builtin_amdgcn_mfma_f32_16x16x32_f16(al[mi], bl, a, 0, 0, 0);
                    a = __builtin_amdgcn_mfma_f32_16x16x32_f16(al[mi], bh, a, 0, 0, 0);
                    a = __builtin_amdgcn_mfma_f32_16x16x32_f16(ah[mi], bl, a, 0, 0, 0);
                    a = __builtin_amdgcn_mfma_f32_16x16x32_f16(ah[mi], bh, a, 0, 0, 0);
                    acc[mi][nj] = a;
                }
            }
        }

        // epilogue: s = 0.5*|v|^2 - dot; running first-argmin (ascending c per lane).
        // C/D layout: col = lane&15, row = (lane>>4)*4 + reg
        #pragma unroll
        for (int nj = 0; nj < 4; ++nj) {
            int c = c0 + (wn * 4 + nj) * 16 + (lane & 15);
            float hv = hv2[c];
            #pragma unroll
            for (int mi = 0; mi < 4; ++mi)
                #pragma unroll
                for (int r = 0; r < 4; ++r) {
                    float s = hv - acc[mi][nj][r];
                    int b = mi * 4 + r;
                    if (s < best[b]) { best[b] = s; bidx[b] = c; }
                }
        }
    }

    // reduce across the 16 col-lanes (same rows, 16 different cols)
    #pragma unroll
    for (int off = 1; off < 16; off <<= 1) {
        #pragma unroll
        for (int b = 0; b < 16; ++b) {
            float ob = __shfl_xor(best[b], off, 64);
            int   oi = __shfl_xor(bidx[b], off, 64);
            if (ob < best[b] || (ob == best[b] && oi < bidx[b])) {
                best[b] = ob; bidx[b] = oi;
            }
        }
    }
    if ((lane & 15) == 0) {
        const size_t sl = (size_t)(blockIdx.y * 4 + wn) * T_TOTAL;  // disjoint per wn
        #pragma unroll
        for (int mi = 0; mi < 4; ++mi)
            #pragma unroll
            for (int r = 0; r < 4; ++r) {
                int q = q0 + mi * 16 + (lane >> 4) * 4 + r;
                partial[sl + q] = make_float2(best[mi * 4 + r], (float)bidx[mi * 4 + r]);
            }
    }
}

// ------- kernel 3: fold 16 partial slices (value min, tie -> smaller global index) -------
__global__ void reduce_kernel(const float2* __restrict__ partial, int* __restrict__ idx) {
    int q = blockIdx.x * 256 + threadIdx.x;
    float bm = 3.4e38f;
    int   bi = 0x7fffffff;
    #pragma unroll
    for (int s = 0; s < NSLICE; ++s) {
        float2 p = partial[(size_t)s * T_TOTAL + q];
        int pi = (int)p.y;
        if (p.x < bm || (p.x == bm && pi < bi)) { bm = p.x; bi = pi; }
    }
    idx[q] = bi;
}

// ---------------- kernel 4: gather vocab rows + emit indices as f32 ----------------
__global__ void gather_kernel(const float* __restrict__ vocab,
                              const int* __restrict__ idx,
                              float* __restrict__ out) {
    int r    = blockIdx.x * 4 + (threadIdx.x >> 6);  // one wave per output row
    int lane = threadIdx.x & 63;
    int k = idx[r];
    const float4* src = (const float4*)(vocab + (size_t)k * D);
    float4*       dst = (float4*)(out + (size_t)r * D);
    dst[lane] = src[lane];
    if (lane == 0) out[(size_t)T_TOTAL * D + r] = (float)k;
}

extern "C" void kernel_launch(void* const* d_in, const int* in_sizes, int n_in,
                              void* d_out, int out_size, void* d_ws, size_t ws_size,
                              hipStream_t stream) {
    const float* seq   = (const float*)d_in[0];   // [T, D] f32
    const float* vocab = (const float*)d_in[1];   // [K, D] f32
    float* out = (float*)d_out;

    float* hv2 = (float*)d_ws;                               // K floats
    int*   idx = (int*)((char*)d_ws + K * sizeof(float));    // T ints

    float2*   partial = (float2*)d_out;                      // 4 MB at head
    _Float16* bhi = (_Float16*)(out + PARTIAL_F);            // 4 MB
    _Float16* blo = bhi + BHALVES;                           // 4 MB
    // all scratch inside d_out's 33.7 MB quantized region; consumed before gather overwrites

    hipLaunchKernelGGL(hv2_kernel,    dim3(K / 4),                dim3(256), 0, stream, vocab, hv2);
    hipLaunchKernelGGL(bsplit_kernel, dim3(NCT),                  dim3(256), 0, stream, vocab, bhi, blo);
    hipLaunchKernelGGL(argmin_kernel, dim3(T_TOTAL / BQ, KSPLIT), dim3(256), 0, stream,
                       seq, bhi, blo, hv2, partial);
    hipLaunchKernelGGL(reduce_kernel, dim3(T_TOTAL / 256),        dim3(256), 0, stream, partial, idx);
    hipLaunchKernelGGL(gather_kernel, dim3(T_TOTAL / 4),          dim3(256), 0, stream, vocab, idx, out);
}

// Round 10
// 485.084 us; speedup vs baseline: 4.5350x; 4.0860x over previous
//
#include <hip/hip_runtime.h>

// Problem constants: N=512, BS=64, DIM=256, SIZE=8192
#define T_TOTAL 32768   // N*BS queries
#define D       256
#define K       8192
#define BQ      64      // queries per block tile (4 row-tiles of 16) — shared by all 4 waves
#define KSPLIT  4
#define KSLICE  (K / KSPLIT)
#define NSLICE  (KSPLIT * 4)        // 4 wn-quadrants write disjoint partial slices
#define NCT     (K / 16)            // 512 code-tiles
#define KT_STRIDE (NCT * 64 * 8)    // halves per kt plane = 262144

typedef _Float16 half4f  __attribute__((ext_vector_type(4)));
typedef _Float16 half8f  __attribute__((ext_vector_type(8)));
typedef float    floatx4 __attribute__((ext_vector_type(4)));

// d_out scratch layout (floats): [0, 1048576) partial (16 slices x T x float2),
// then Bhi (1048576 f), then Blo (1048576 f). All consumed before gather overwrites.
#define PARTIAL_F 1048576
#define BHALVES   2097152   // halves per B array (8*512*64*8)

// ---------------- kernel 1: half squared norms of vocab rows (fp32 exact) ----------------
__global__ void hv2_kernel(const float* __restrict__ vocab, float* __restrict__ hv2) {
    int code = blockIdx.x * 4 + (threadIdx.x >> 6);
    int lane = threadIdx.x & 63;
    const float4* row = (const float4*)(vocab + (size_t)code * D);
    float4 v = row[lane];
    float s = v.x * v.x + v.y * v.y + v.z * v.z + v.w * v.w;
    #pragma unroll
    for (int off = 32; off; off >>= 1) s += __shfl_down(s, off, 64);
    if (lane == 0) hv2[code] = 0.5f * s;
}

__device__ __forceinline__ _Float16 hi16(float x) { return (_Float16)x; }
__device__ __forceinline__ _Float16 lo16(float x, _Float16 h) { return (_Float16)(x - (float)h); }
__device__ __forceinline__ void split4(float4 v, half4f& h, half4f& l) {
    _Float16 hx = hi16(v.x), hy = hi16(v.y), hz = hi16(v.z), hw = hi16(v.w);
    h = (half4f){hx, hy, hz, hw};
    l = (half4f){lo16(v.x, hx), lo16(v.y, hy), lo16(v.z, hz), lo16(v.w, hw)};
}

// ------- kernel 1b: split vocab into fp16 hi/lo, fragment-order global layout -------
// tile(kt 0..7, ct 0..511): 64 lanes x 8 halves; element (code c, dim k) ->
// kt=k>>5, ct=c>>4, lane=(c&15)+16*((k&31)>>3), j=k&7. Addr=((kt*512+ct)*64+lane)*8+j.
__global__ void bsplit_kernel(const float* __restrict__ vocab,
                              _Float16* __restrict__ bhi, _Float16* __restrict__ blo) {
    const int ct = blockIdx.x;           // 512 blocks, one 16-code tile each
    const int t  = threadIdx.x;
    const int k4 = t & 63;               // float4 index along D
    const float4* voc4 = (const float4*)vocab;
    const int kt = k4 >> 3, kg = (k4 >> 1) & 3, h = k4 & 1;
    #pragma unroll
    for (int ci = 0; ci < 4; ++ci) {
        int cc = (t >> 6) * 4 + ci;      // code within tile
        float4 v = voc4[(size_t)(ct * 16 + cc) * (D / 4) + k4];
        half4f hh, ll;
        split4(v, hh, ll);
        size_t off = (((size_t)kt * NCT + ct) * 64 + (cc + 16 * kg)) * 8 + h * 4;
        *(half4f*)&bhi[off] = hh;
        *(half4f*)&blo[off] = ll;
    }
}

// -------- kernel 2: MFMA argmin, barrier-free K-loop, 64q x 64c per wave --------
// block 256 = 4 waves; wave wn 0..3 covers a code quadrant; all waves share 64 A rows.
// grid (T/BQ, KSPLIT). Wave writes partial slice (blockIdx.y*4 + wn) -> 16 disjoint slices.
// NOTE: kt loop is NOT unrolled — full unroll let the scheduler hoist 64 global loads
// and spill ~4.7 GB of scratch (R8/R9 measured). Small loop body = small live set.
__launch_bounds__(256, 2)
__global__ void argmin_kernel(const float* __restrict__ seq,
                              const _Float16* __restrict__ bhi,
                              const _Float16* __restrict__ blo,
                              const float* __restrict__ hv2,
                              float2* __restrict__ partial) {
    // A LDS in fragment order [rt 0..3][kt 0..7][flane 0..63][8], XOR-swizzled by kt<<3
    __shared__ _Float16 AhL[4 * 8 * 64 * 8];   // 32 KB
    __shared__ _Float16 AlL[4 * 8 * 64 * 8];   // 32 KB

    const int t    = threadIdx.x;
    const int lane = t & 63;
    const int wn   = t >> 6;            // code quadrant 0..3
    const int q0   = blockIdx.x * BQ;
    const int k0   = blockIdx.y * KSLICE;

    const float4* seq4 = (const float4*)seq;

    // ---- prologue: split A (64 rows x 256 dims) into fragment-order LDS, once ----
    #pragma unroll
    for (int i = 0; i < 16; ++i) {
        int f   = t + 256 * i;          // 0..4095 float4s
        int row = f >> 6;               // 0..63
        int d4  = f & 63;               // float4 along D
        float4 v = seq4[(size_t)(q0 + row) * (D / 4) + d4];
        half4f h, l;
        split4(v, h, l);
        int kt = d4 >> 3, kg = (d4 >> 1) & 3, hh = d4 & 1;
        int off = (((((row >> 4) * 8 + kt) * 64) + ((row & 15) + 16 * kg)) * 8 + hh * 4)
                  ^ (kt << 3);          // swizzle: write conflicts 32-way -> 4-way (R8-verified)
        *(half4f*)&AhL[off] = h;
        *(half4f*)&AlL[off] = l;
    }
    __syncthreads();   // the ONLY barrier

    float best[16];
    int   bidx[16];
    #pragma unroll
    for (int b = 0; b < 16; ++b) { best[b] = 3.4e38f; bidx[b] = 0; }

    const _Float16* bh_l = bhi + (size_t)lane * 8;
    const _Float16* bl_l = blo + (size_t)lane * 8;

    for (int c0i = 0; c0i < KSLICE / 256; ++c0i) {   // 8 c0 tiles of 256 codes
        const int c0  = k0 + c0i * 256;
        const int ct0 = (c0 >> 4) + wn * 4;          // this wave's 4 code-tiles

        floatx4 acc[4][4];
        #pragma unroll
        for (int mi = 0; mi < 4; ++mi)
            #pragma unroll
            for (int nj = 0; nj < 4; ++nj) acc[mi][nj] = (floatx4){0.f, 0.f, 0.f, 0.f};

        #pragma unroll 1   // REAL loop: limit load-hoisting window (anti-spill, R9 lesson)
        for (int kt = 0; kt < 8; ++kt) {
            // A fragments from LDS ((lane^kt)*16B permutation: conflict-free b128)
            half8f ah[4], al[4];
            #pragma unroll
            for (int mi = 0; mi < 4; ++mi) {
                const int ao = (((mi * 8 + kt) * 64 + lane) * 8) ^ (kt << 3);
                ah[mi] = *(const half8f*)&AhL[ao];
                al[mi] = *(const half8f*)&AlL[ao];
            }
            const size_t kb = (size_t)kt * KT_STRIDE + (size_t)ct0 * 512;
            #pragma unroll
            for (int nj = 0; nj < 4; ++nj) {
                // B direct from global (coalesced b128, L2-resident); <=8 live B regs
                half8f bh = *(const half8f*)&bh_l[kb + nj * 512];
                half8f bl = *(const half8f*)&bl_l[kb + nj * 512];
                #pragma unroll
                for (int mi = 0; mi < 4; ++mi) {
                    floatx4 a = acc[mi][nj];
                    a = __builtin_amdgcn_mfma_f32_16x16x32_f16(al[mi], bl, a, 0, 0, 0);
                    a = __builtin_amdgcn_mfma_f32_16x16x32_f16(al[mi], bh, a, 0, 0, 0);
                    a = __builtin_amdgcn_mfma_f32_16x16x32_f16(ah[mi], bl, a, 0, 0, 0);
                    a = __builtin_amdgcn_mfma_f32_16x16x32_f16(ah[mi], bh, a, 0, 0, 0);
                    acc[mi][nj] = a;
                }
            }
        }

        // epilogue: s = 0.5*|v|^2 - dot; running first-argmin (ascending c per lane).
        // C/D layout: col = lane&15, row = (lane>>4)*4 + reg
        #pragma unroll
        for (int nj = 0; nj < 4; ++nj) {
            int c = c0 + (wn * 4 + nj) * 16 + (lane & 15);
            float hv = hv2[c];
            #pragma unroll
            for (int mi = 0; mi < 4; ++mi)
                #pragma unroll
                for (int r = 0; r < 4; ++r) {
                    float s = hv - acc[mi][nj][r];
                    int b = mi * 4 + r;
                    if (s < best[b]) { best[b] = s; bidx[b] = c; }
                }
        }
    }

    // reduce across the 16 col-lanes (same rows, 16 different cols)
    #pragma unroll
    for (int off = 1; off < 16; off <<= 1) {
        #pragma unroll
        for (int b = 0; b < 16; ++b) {
            float ob = __shfl_xor(best[b], off, 64);
            int   oi = __shfl_xor(bidx[b], off, 64);
            if (ob < best[b] || (ob == best[b] && oi < bidx[b])) {
                best[b] = ob; bidx[b] = oi;
            }
        }
    }
    if ((lane & 15) == 0) {
        const size_t sl = (size_t)(blockIdx.y * 4 + wn) * T_TOTAL;  // disjoint per wn
        #pragma unroll
        for (int mi = 0; mi < 4; ++mi)
            #pragma unroll
            for (int r = 0; r < 4; ++r) {
                int q = q0 + mi * 16 + (lane >> 4) * 4 + r;
                partial[sl + q] = make_float2(best[mi * 4 + r], (float)bidx[mi * 4 + r]);
            }
    }
}

// ------- kernel 3: fold 16 partial slices (value min, tie -> smaller global index) -------
__global__ void reduce_kernel(const float2* __restrict__ partial, int* __restrict__ idx) {
    int q = blockIdx.x * 256 + threadIdx.x;
    float bm = 3.4e38f;
    int   bi = 0x7fffffff;
    #pragma unroll
    for (int s = 0; s < NSLICE; ++s) {
        float2 p = partial[(size_t)s * T_TOTAL + q];
        int pi = (int)p.y;
        if (p.x < bm || (p.x == bm && pi < bi)) { bm = p.x; bi = pi; }
    }
    idx[q] = bi;
}

// ---------------- kernel 4: gather vocab rows + emit indices as f32 ----------------
__global__ void gather_kernel(const float* __restrict__ vocab,
                              const int* __restrict__ idx,
                              float* __restrict__ out) {
    int r    = blockIdx.x * 4 + (threadIdx.x >> 6);  // one wave per output row
    int lane = threadIdx.x & 63;
    int k = idx[r];
    const float4* src = (const float4*)(vocab + (size_t)k * D);
    float4*       dst = (float4*)(out + (size_t)r * D);
    dst[lane] = src[lane];
    if (lane == 0) out[(size_t)T_TOTAL * D + r] = (float)k;
}

extern "C" void kernel_launch(void* const* d_in, const int* in_sizes, int n_in,
                              void* d_out, int out_size, void* d_ws, size_t ws_size,
                              hipStream_t stream) {
    const float* seq   = (const float*)d_in[0];   // [T, D] f32
    const float* vocab = (const float*)d_in[1];   // [K, D] f32
    float* out = (float*)d_out;

    float* hv2 = (float*)d_ws;                               // K floats
    int*   idx = (int*)((char*)d_ws + K * sizeof(float));    // T ints

    float2*   partial = (float2*)d_out;                      // 4 MB at head
    _Float16* bhi = (_Float16*)(out + PARTIAL_F);            // 4 MB
    _Float16* blo = bhi + BHALVES;                           // 4 MB
    // all scratch inside d_out's 33.7 MB quantized region; consumed before gather overwrites

    hipLaunchKernelGGL(hv2_kernel,    dim3(K / 4),                dim3(256), 0, stream, vocab, hv2);
    hipLaunchKernelGGL(bsplit_kernel, dim3(NCT),                  dim3(256), 0, stream, vocab, bhi, blo);
    hipLaunchKernelGGL(argmin_kernel, dim3(T_TOTAL / BQ, KSPLIT), dim3(256), 0, stream,
                       seq, bhi, blo, hv2, partial);
    hipLaunchKernelGGL(reduce_kernel, dim3(T_TOTAL / 256),        dim3(256), 0, stream, partial, idx);
    hipLaunchKernelGGL(gather_kernel, dim3(T_TOTAL / 4),          dim3(256), 0, stream, vocab, idx, out);
}

// Round 11
// 461.343 us; speedup vs baseline: 4.7683x; 1.0515x over previous
//
#include <hip/hip_runtime.h>

// Problem constants: N=512, BS=64, DIM=256, SIZE=8192
#define T_TOTAL 32768   // N*BS queries
#define D       256
#define K       8192
#define BQ      64      // queries per block tile (4 row-tiles of 16) — shared by all 4 waves
#define KSPLIT  4
#define KSLICE  (K / KSPLIT)
#define NSLICE  (KSPLIT * 4)        // 4 wn-quadrants write disjoint partial slices
#define NCT     (K / 16)            // 512 code-tiles
#define KT_STRIDE (NCT * 64 * 8)    // halves per kt plane = 262144
#define NQB     (T_TOTAL / BQ)      // 512 query-blocks

typedef _Float16 half4f  __attribute__((ext_vector_type(4)));
typedef _Float16 half8f  __attribute__((ext_vector_type(8)));
typedef float    floatx4 __attribute__((ext_vector_type(4)));

// d_out scratch layout (floats): [0, 1048576) partial (16 slices x T x float2),
// then Bhi (1048576 f), then Blo (1048576 f). All consumed before gather overwrites.
#define PARTIAL_F 1048576
#define BHALVES   2097152   // halves per B array (8*512*64*8)

// ---------------- kernel 1: half squared norms of vocab rows (fp32 exact) ----------------
__global__ void hv2_kernel(const float* __restrict__ vocab, float* __restrict__ hv2) {
    int code = blockIdx.x * 4 + (threadIdx.x >> 6);
    int lane = threadIdx.x & 63;
    const float4* row = (const float4*)(vocab + (size_t)code * D);
    float4 v = row[lane];
    float s = v.x * v.x + v.y * v.y + v.z * v.z + v.w * v.w;
    #pragma unroll
    for (int off = 32; off; off >>= 1) s += __shfl_down(s, off, 64);
    if (lane == 0) hv2[code] = 0.5f * s;
}

__device__ __forceinline__ _Float16 hi16(float x) { return (_Float16)x; }
__device__ __forceinline__ _Float16 lo16(float x, _Float16 h) { return (_Float16)(x - (float)h); }
__device__ __forceinline__ void split4(float4 v, half4f& h, half4f& l) {
    _Float16 hx = hi16(v.x), hy = hi16(v.y), hz = hi16(v.z), hw = hi16(v.w);
    h = (half4f){hx, hy, hz, hw};
    l = (half4f){lo16(v.x, hx), lo16(v.y, hy), lo16(v.z, hz), lo16(v.w, hw)};
}

// ------- kernel 1b: split vocab into fp16 hi/lo, fragment-order global layout -------
// tile(kt 0..7, ct 0..511): 64 lanes x 8 halves; element (code c, dim k) ->
// kt=k>>5, ct=c>>4, lane=(c&15)+16*((k&31)>>3), j=k&7. Addr=((kt*512+ct)*64+lane)*8+j.
__global__ void bsplit_kernel(const float* __restrict__ vocab,
                              _Float16* __restrict__ bhi, _Float16* __restrict__ blo) {
    const int ct = blockIdx.x;           // 512 blocks, one 16-code tile each
    const int t  = threadIdx.x;
    const int k4 = t & 63;               // float4 index along D
    const float4* voc4 = (const float4*)vocab;
    const int kt = k4 >> 3, kg = (k4 >> 1) & 3, h = k4 & 1;
    #pragma unroll
    for (int ci = 0; ci < 4; ++ci) {
        int cc = (t >> 6) * 4 + ci;      // code within tile
        float4 v = voc4[(size_t)(ct * 16 + cc) * (D / 4) + k4];
        half4f hh, ll;
        split4(v, hh, ll);
        size_t off = (((size_t)kt * NCT + ct) * 64 + (cc + 16 * kg)) * 8 + h * 4;
        *(half4f*)&bhi[off] = hh;
        *(half4f*)&blo[off] = ll;
    }
}

// -------- kernel 2: MFMA argmin, barrier-free K-loop, 64q x 64c per wave, 3-term split ----
// block 256 = 4 waves; wave wn 0..3 covers a code quadrant; all waves share 64 A rows.
// grid: 2048 flattened; XCD swizzle: slice=(i&7)>>1, qb=(i>>3)*2+(i&1) — if dispatch
// round-robins XCDs by linear block id, each XCD sees ONE K-slice -> its 2 MB B-slice
// stays resident in the 4 MB per-XCD L2 (heuristic only; bijective = always correct).
// kt loop NOT unrolled: full unroll hoists 64 global loads -> 4.7 GB spill (R8/R9).
__launch_bounds__(256, 2)
__global__ void argmin_kernel(const float* __restrict__ seq,
                              const _Float16* __restrict__ bhi,
                              const _Float16* __restrict__ blo,
                              const float* __restrict__ hv2,
                              float2* __restrict__ partial) {
    // A LDS in fragment order [rt 0..3][kt 0..7][flane 0..63][8], XOR-swizzled by kt<<3
    __shared__ _Float16 AhL[4 * 8 * 64 * 8];   // 32 KB
    __shared__ _Float16 AlL[4 * 8 * 64 * 8];   // 32 KB

    const int t    = threadIdx.x;
    const int lane = t & 63;
    const int wn   = t >> 6;            // code quadrant 0..3
    const int bi   = blockIdx.x;
    const int slice = (bi & 7) >> 1;    // 0..3  (XCD-locked K-slice)
    const int qb    = (bi >> 3) * 2 + (bi & 1);  // 0..511
    const int q0   = qb * BQ;
    const int k0   = slice * KSLICE;

    const float4* seq4 = (const float4*)seq;

    // ---- prologue: split A (64 rows x 256 dims) into fragment-order LDS, once ----
    #pragma unroll
    for (int i = 0; i < 16; ++i) {
        int f   = t + 256 * i;          // 0..4095 float4s
        int row = f >> 6;               // 0..63
        int d4  = f & 63;               // float4 along D
        float4 v = seq4[(size_t)(q0 + row) * (D / 4) + d4];
        half4f h, l;
        split4(v, h, l);
        int kt = d4 >> 3, kg = (d4 >> 1) & 3, hh = d4 & 1;
        int off = (((((row >> 4) * 8 + kt) * 64) + ((row & 15) + 16 * kg)) * 8 + hh * 4)
                  ^ (kt << 3);          // swizzle: write conflicts 32-way -> 4-way (R8-verified)
        *(half4f*)&AhL[off] = h;
        *(half4f*)&AlL[off] = l;
    }
    __syncthreads();   // the ONLY barrier

    float best[16];
    int   bidx[16];
    #pragma unroll
    for (int b = 0; b < 16; ++b) { best[b] = 3.4e38f; bidx[b] = 0; }

    const _Float16* bh_l = bhi + (size_t)lane * 8;
    const _Float16* bl_l = blo + (size_t)lane * 8;

    for (int c0i = 0; c0i < KSLICE / 256; ++c0i) {   // 8 c0 tiles of 256 codes
        const int c0  = k0 + c0i * 256;
        const int ct0 = (c0 >> 4) + wn * 4;          // this wave's 4 code-tiles

        floatx4 acc[4][4];
        #pragma unroll
        for (int mi = 0; mi < 4; ++mi)
            #pragma unroll
            for (int nj = 0; nj < 4; ++nj) acc[mi][nj] = (floatx4){0.f, 0.f, 0.f, 0.f};

        #pragma unroll 1   // REAL loop: limit load-hoisting window (anti-spill, R9 lesson)
        for (int kt = 0; kt < 8; ++kt) {
            // A fragments from LDS ((lane^kt)*16B permutation: conflict-free b128)
            half8f ah[4], al[4];
            #pragma unroll
            for (int mi = 0; mi < 4; ++mi) {
                const int ao = (((mi * 8 + kt) * 64 + lane) * 8) ^ (kt << 3);
                ah[mi] = *(const half8f*)&AhL[ao];
                al[mi] = *(const half8f*)&AlL[ao];
            }
            const size_t kb = (size_t)kt * KT_STRIDE + (size_t)ct0 * 512;
            #pragma unroll
            for (int nj = 0; nj < 4; ++nj) {
                // B direct from global (coalesced b128, L2-resident); <=8 live B regs
                half8f bh = *(const half8f*)&bh_l[kb + nj * 512];
                half8f bl = *(const half8f*)&bl_l[kb + nj * 512];
                #pragma unroll
                for (int mi = 0; mi < 4; ++mi) {
                    // 3-term Markidis split: ll term dropped (error ~2e-6 << argmin gaps)
                    floatx4 a = acc[mi][nj];
                    a = __builtin_amdgcn_mfma_f32_16x16x32_f16(al[mi], bh, a, 0, 0, 0);
                    a = __builtin_amdgcn_mfma_f32_16x16x32_f16(ah[mi], bl, a, 0, 0, 0);
                    a = __builtin_amdgcn_mfma_f32_16x16x32_f16(ah[mi], bh, a, 0, 0, 0);
                    acc[mi][nj] = a;
                }
            }
        }

        // epilogue: s = 0.5*|v|^2 - dot; running first-argmin (ascending c per lane).
        // C/D layout: col = lane&15, row = (lane>>4)*4 + reg
        #pragma unroll
        for (int nj = 0; nj < 4; ++nj) {
            int c = c0 + (wn * 4 + nj) * 16 + (lane & 15);
            float hv = hv2[c];
            #pragma unroll
            for (int mi = 0; mi < 4; ++mi)
                #pragma unroll
                for (int r = 0; r < 4; ++r) {
                    float s = hv - acc[mi][nj][r];
                    int b = mi * 4 + r;
                    if (s < best[b]) { best[b] = s; bidx[b] = c; }
                }
        }
    }

    // reduce across the 16 col-lanes (same rows, 16 different cols)
    #pragma unroll
    for (int off = 1; off < 16; off <<= 1) {
        #pragma unroll
        for (int b = 0; b < 16; ++b) {
            float ob = __shfl_xor(best[b], off, 64);
            int   oi = __shfl_xor(bidx[b], off, 64);
            if (ob < best[b] || (ob == best[b] && oi < bidx[b])) {
                best[b] = ob; bidx[b] = oi;
            }
        }
    }
    if ((lane & 15) == 0) {
        const size_t sl = (size_t)(slice * 4 + wn) * T_TOTAL;  // disjoint per (slice, wn)
        #pragma unroll
        for (int mi = 0; mi < 4; ++mi)
            #pragma unroll
            for (int r = 0; r < 4; ++r) {
                int q = q0 + mi * 16 + (lane >> 4) * 4 + r;
                partial[sl + q] = make_float2(best[mi * 4 + r], (float)bidx[mi * 4 + r]);
            }
    }
}

// ------- kernel 3: fold 16 partial slices (value min, tie -> smaller global index) -------
__global__ void reduce_kernel(const float2* __restrict__ partial, int* __restrict__ idx) {
    int q = blockIdx.x * 256 + threadIdx.x;
    float bm = 3.4e38f;
    int   bi = 0x7fffffff;
    #pragma unroll
    for (int s = 0; s < NSLICE; ++s) {
        float2 p = partial[(size_t)s * T_TOTAL + q];
        int pi = (int)p.y;
        if (p.x < bm || (p.x == bm && pi < bi)) { bm = p.x; bi = pi; }
    }
    idx[q] = bi;
}

// ---------------- kernel 4: gather vocab rows + emit indices as f32 ----------------
__global__ void gather_kernel(const float* __restrict__ vocab,
                              const int* __restrict__ idx,
                              float* __restrict__ out) {
    int r    = blockIdx.x * 4 + (threadIdx.x >> 6);  // one wave per output row
    int lane = threadIdx.x & 63;
    int k = idx[r];
    const float4* src = (const float4*)(vocab + (size_t)k * D);
    float4*       dst = (float4*)(out + (size_t)r * D);
    dst[lane] = src[lane];
    if (lane == 0) out[(size_t)T_TOTAL * D + r] = (float)k;
}

extern "C" void kernel_launch(void* const* d_in, const int* in_sizes, int n_in,
                              void* d_out, int out_size, void* d_ws, size_t ws_size,
                              hipStream_t stream) {
    const float* seq   = (const float*)d_in[0];   // [T, D] f32
    const float* vocab = (const float*)d_in[1];   // [K, D] f32
    float* out = (float*)d_out;

    float* hv2 = (float*)d_ws;                               // K floats
    int*   idx = (int*)((char*)d_ws + K * sizeof(float));    // T ints

    float2*   partial = (float2*)d_out;                      // 4 MB at head
    _Float16* bhi = (_Float16*)(out + PARTIAL_F);            // 4 MB
    _Float16* blo = bhi + BHALVES;                           // 4 MB
    // all scratch inside d_out's 33.7 MB quantized region; consumed before gather overwrites

    hipLaunchKernelGGL(hv2_kernel,    dim3(K / 4),           dim3(256), 0, stream, vocab, hv2);
    hipLaunchKernelGGL(bsplit_kernel, dim3(NCT),             dim3(256), 0, stream, vocab, bhi, blo);
    hipLaunchKernelGGL(argmin_kernel, dim3(NQB * KSPLIT),    dim3(256), 0, stream,
                       seq, bhi, blo, hv2, partial);
    hipLaunchKernelGGL(reduce_kernel, dim3(T_TOTAL / 256),   dim3(256), 0, stream, partial, idx);
    hipLaunchKernelGGL(gather_kernel, dim3(T_TOTAL / 4),     dim3(256), 0, stream, vocab, idx, out);
}

// Round 12
// 445.902 us; speedup vs baseline: 4.9335x; 1.0346x over previous
//
#include <hip/hip_runtime.h>

// Problem constants: N=512, BS=64, DIM=256, SIZE=8192
#define T_TOTAL 32768   // N*BS queries
#define D       256
#define K       8192
#define BQ      64      // queries per block tile (4 row-tiles of 16) — shared by all 4 waves
#define KSPLIT  4
#define KSLICE  (K / KSPLIT)
#define NSLICE  (KSPLIT * 4)        // (slice, wn) pairs write disjoint partial slices
#define NCT     (K / 16)            // 512 code-tiles
#define KT_STRIDE (NCT * 64 * 8)    // halves per kt plane = 262144
#define NQB     (T_TOTAL / BQ)      // 512 query-blocks

typedef _Float16 half4f  __attribute__((ext_vector_type(4)));
typedef _Float16 half8f  __attribute__((ext_vector_type(8)));
typedef float    floatx4 __attribute__((ext_vector_type(4)));

// d_out scratch layout (floats): [0, 1048576) partial (16 slices x T x float2),
// then Bhi (1048576 f), then Blo (1048576 f). All consumed before gather overwrites.
#define PARTIAL_F 1048576
#define BHALVES   2097152   // halves per B array (8*512*64*8)

// ---------------- kernel 1: half squared norms of vocab rows (fp32 exact) ----------------
__global__ void hv2_kernel(const float* __restrict__ vocab, float* __restrict__ hv2) {
    int code = blockIdx.x * 4 + (threadIdx.x >> 6);
    int lane = threadIdx.x & 63;
    const float4* row = (const float4*)(vocab + (size_t)code * D);
    float4 v = row[lane];
    float s = v.x * v.x + v.y * v.y + v.z * v.z + v.w * v.w;
    #pragma unroll
    for (int off = 32; off; off >>= 1) s += __shfl_down(s, off, 64);
    if (lane == 0) hv2[code] = 0.5f * s;
}

__device__ __forceinline__ _Float16 hi16(float x) { return (_Float16)x; }
__device__ __forceinline__ _Float16 lo16(float x, _Float16 h) { return (_Float16)(x - (float)h); }
__device__ __forceinline__ void split4(float4 v, half4f& h, half4f& l) {
    _Float16 hx = hi16(v.x), hy = hi16(v.y), hz = hi16(v.z), hw = hi16(v.w);
    h = (half4f){hx, hy, hz, hw};
    l = (half4f){lo16(v.x, hx), lo16(v.y, hy), lo16(v.z, hz), lo16(v.w, hw)};
}

// ------- kernel 1b: split vocab into fp16 hi/lo, fragment-order global layout -------
__global__ void bsplit_kernel(const float* __restrict__ vocab,
                              _Float16* __restrict__ bhi, _Float16* __restrict__ blo) {
    const int ct = blockIdx.x;           // 512 blocks, one 16-code tile each
    const int t  = threadIdx.x;
    const int k4 = t & 63;               // float4 index along D
    const float4* voc4 = (const float4*)vocab;
    const int kt = k4 >> 3, kg = (k4 >> 1) & 3, h = k4 & 1;
    #pragma unroll
    for (int ci = 0; ci < 4; ++ci) {
        int cc = (t >> 6) * 4 + ci;      // code within tile
        float4 v = voc4[(size_t)(ct * 16 + cc) * (D / 4) + k4];
        half4f hh, ll;
        split4(v, hh, ll);
        size_t off = (((size_t)kt * NCT + ct) * 64 + (cc + 16 * kg)) * 8 + h * 4;
        *(half4f*)&bhi[off] = hh;
        *(half4f*)&blo[off] = ll;
    }
}

// -------- kernel 2: MFMA argmin; 3-term split; depth-1 B software pipeline --------
// block 256 = 4 waves; wave wn 0..3 covers a code quadrant; all waves share 64 A rows.
// grid 2048 flattened; XCD swizzle locks one K-slice per XCD (B slice 2 MB < 4 MB L2).
// kt2 loop rolled (unroll 1): at most 8 B-loads in flight -> bounded live set (R8 lesson);
// ping-pong B buffers hide L2 latency behind the other kt's MFMA burst (R11 lesson).
__launch_bounds__(256, 2)
__global__ void argmin_kernel(const float* __restrict__ seq,
                              const _Float16* __restrict__ bhi,
                              const _Float16* __restrict__ blo,
                              const float* __restrict__ hv2,
                              float2* __restrict__ partial) {
    // A LDS in fragment order [rt 0..3][kt 0..7][flane 0..63][8], XOR-swizzled by kt<<3
    __shared__ _Float16 AhL[4 * 8 * 64 * 8];   // 32 KB
    __shared__ _Float16 AlL[4 * 8 * 64 * 8];   // 32 KB

    const int t    = threadIdx.x;
    const int lane = t & 63;
    const int wn   = t >> 6;            // code quadrant 0..3
    const int bi   = blockIdx.x;
    const int slice = (bi & 7) >> 1;    // 0..3  (XCD-locked K-slice)
    const int qb    = (bi >> 3) * 2 + (bi & 1);  // 0..511
    const int q0   = qb * BQ;
    const int k0   = slice * KSLICE;

    const float4* seq4 = (const float4*)seq;

    // ---- prologue: split A (64 rows x 256 dims) into fragment-order LDS, once ----
    #pragma unroll
    for (int i = 0; i < 16; ++i) {
        int f   = t + 256 * i;          // 0..4095 float4s
        int row = f >> 6;               // 0..63
        int d4  = f & 63;               // float4 along D
        float4 v = seq4[(size_t)(q0 + row) * (D / 4) + d4];
        half4f h, l;
        split4(v, h, l);
        int kt = d4 >> 3, kg = (d4 >> 1) & 3, hh = d4 & 1;
        int off = (((((row >> 4) * 8 + kt) * 64) + ((row & 15) + 16 * kg)) * 8 + hh * 4)
                  ^ (kt << 3);          // swizzle: write conflicts 32-way -> 4-way
        *(half4f*)&AhL[off] = h;
        *(half4f*)&AlL[off] = l;
    }
    __syncthreads();   // the ONLY barrier

    float best[16];
    int   bidx[16];
    #pragma unroll
    for (int b = 0; b < 16; ++b) { best[b] = 3.4e38f; bidx[b] = 0; }

    const _Float16* bh_l = bhi + (size_t)lane * 8;
    const _Float16* bl_l = blo + (size_t)lane * 8;

    for (int c0i = 0; c0i < KSLICE / 256; ++c0i) {   // 8 c0 tiles of 256 codes
        const int c0  = k0 + c0i * 256;
        const int ct0 = (c0 >> 4) + wn * 4;          // this wave's 4 code-tiles
        const size_t cb = (size_t)ct0 * 512;

        floatx4 acc[4][4];
        #pragma unroll
        for (int mi = 0; mi < 4; ++mi)
            #pragma unroll
            for (int nj = 0; nj < 4; ++nj) acc[mi][nj] = (floatx4){0.f, 0.f, 0.f, 0.f};

        // ping-pong B buffers (depth-1 pipeline)
        half8f bh0[4], bl0[4], bh1[4], bl1[4];
        #pragma unroll
        for (int nj = 0; nj < 4; ++nj) {          // preload kt=0 into buf0
            bh0[nj] = *(const half8f*)&bh_l[cb + nj * 512];
            bl0[nj] = *(const half8f*)&bl_l[cb + nj * 512];
        }

        #pragma unroll 1   // REAL loop: bounded hoist window (anti-spill, R9 lesson)
        for (int kt2 = 0; kt2 < 4; ++kt2) {
            const int kt = kt2 * 2;
            // prefetch kt+1 into buf1 (overlaps with kt's MFMA burst below)
            {
                const size_t kb = (size_t)(kt + 1) * KT_STRIDE + cb;
                #pragma unroll
                for (int nj = 0; nj < 4; ++nj) {
                    bh1[nj] = *(const half8f*)&bh_l[kb + nj * 512];
                    bl1[nj] = *(const half8f*)&bl_l[kb + nj * 512];
                }
            }
            // A frags for kt; MFMA with buf0
            {
                half8f ah[4], al[4];
                #pragma unroll
                for (int mi = 0; mi < 4; ++mi) {
                    const int ao = (((mi * 8 + kt) * 64 + lane) * 8) ^ (kt << 3);
                    ah[mi] = *(const half8f*)&AhL[ao];
                    al[mi] = *(const half8f*)&AlL[ao];
                }
                #pragma unroll
                for (int nj = 0; nj < 4; ++nj)
                    #pragma unroll
                    for (int mi = 0; mi < 4; ++mi) {
                        floatx4 a = acc[mi][nj];
                        a = __builtin_amdgcn_mfma_f32_16x16x32_f16(al[mi], bh0[nj], a, 0, 0, 0);
                        a = __builtin_amdgcn_mfma_f32_16x16x32_f16(ah[mi], bl0[nj], a, 0, 0, 0);
                        a = __builtin_amdgcn_mfma_f32_16x16x32_f16(ah[mi], bh0[nj], a, 0, 0, 0);
                        acc[mi][nj] = a;
                    }
            }
            // prefetch kt+2 into buf0 (uniform branch; skipped on last lap)
            if (kt2 < 3) {
                const size_t kb = (size_t)(kt + 2) * KT_STRIDE + cb;
                #pragma unroll
                for (int nj = 0; nj < 4; ++nj) {
                    bh0[nj] = *(const half8f*)&bh_l[kb + nj * 512];
                    bl0[nj] = *(const half8f*)&bl_l[kb + nj * 512];
                }
            }
            // A frags for kt+1; MFMA with buf1
            {
                half8f ah[4], al[4];
                #pragma unroll
                for (int mi = 0; mi < 4; ++mi) {
                    const int ao = (((mi * 8 + kt + 1) * 64 + lane) * 8) ^ ((kt + 1) << 3);
                    ah[mi] = *(const half8f*)&AhL[ao];
                    al[mi] = *(const half8f*)&AlL[ao];
                }
                #pragma unroll
                for (int nj = 0; nj < 4; ++nj)
                    #pragma unroll
                    for (int mi = 0; mi < 4; ++mi) {
                        floatx4 a = acc[mi][nj];
                        a = __builtin_amdgcn_mfma_f32_16x16x32_f16(al[mi], bh1[nj], a, 0, 0, 0);
                        a = __builtin_amdgcn_mfma_f32_16x16x32_f16(ah[mi], bl1[nj], a, 0, 0, 0);
                        a = __builtin_amdgcn_mfma_f32_16x16x32_f16(ah[mi], bh1[nj], a, 0, 0, 0);
                        acc[mi][nj] = a;
                    }
            }
        }

        // epilogue: s = 0.5*|v|^2 - dot; running first-argmin (ascending c per lane).
        // C/D layout: col = lane&15, row = (lane>>4)*4 + reg
        #pragma unroll
        for (int nj = 0; nj < 4; ++nj) {
            int c = c0 + (wn * 4 + nj) * 16 + (lane & 15);
            float hv = hv2[c];
            #pragma unroll
            for (int mi = 0; mi < 4; ++mi)
                #pragma unroll
                for (int r = 0; r < 4; ++r) {
                    float s = hv - acc[mi][nj][r];
                    int b = mi * 4 + r;
                    if (s < best[b]) { best[b] = s; bidx[b] = c; }
                }
        }
    }

    // reduce across the 16 col-lanes (same rows, 16 different cols)
    #pragma unroll
    for (int off = 1; off < 16; off <<= 1) {
        #pragma unroll
        for (int b = 0; b < 16; ++b) {
            float ob = __shfl_xor(best[b], off, 64);
            int   oi = __shfl_xor(bidx[b], off, 64);
            if (ob < best[b] || (ob == best[b] && oi < bidx[b])) {
                best[b] = ob; bidx[b] = oi;
            }
        }
    }
    if ((lane & 15) == 0) {
        const size_t sl = (size_t)(slice * 4 + wn) * T_TOTAL;  // disjoint per (slice, wn)
        #pragma unroll
        for (int mi = 0; mi < 4; ++mi)
            #pragma unroll
            for (int r = 0; r < 4; ++r) {
                int q = q0 + mi * 16 + (lane >> 4) * 4 + r;
                partial[sl + q] = make_float2(best[mi * 4 + r], (float)bidx[mi * 4 + r]);
            }
    }
}

// ------- kernel 3: fold 16 partial slices (value min, tie -> smaller global index) -------
__global__ void reduce_kernel(const float2* __restrict__ partial, int* __restrict__ idx) {
    int q = blockIdx.x * 256 + threadIdx.x;
    float bm = 3.4e38f;
    int   bi = 0x7fffffff;
    #pragma unroll
    for (int s = 0; s < NSLICE; ++s) {
        float2 p = partial[(size_t)s * T_TOTAL + q];
        int pi = (int)p.y;
        if (p.x < bm || (p.x == bm && pi < bi)) { bm = p.x; bi = pi; }
    }
    idx[q] = bi;
}

// ---------------- kernel 4: gather vocab rows + emit indices as f32 ----------------
__global__ void gather_kernel(const float* __restrict__ vocab,
                              const int* __restrict__ idx,
                              float* __restrict__ out) {
    int r    = blockIdx.x * 4 + (threadIdx.x >> 6);  // one wave per output row
    int lane = threadIdx.x & 63;
    int k = idx[r];
    const float4* src = (const float4*)(vocab + (size_t)k * D);
    float4*       dst = (float4*)(out + (size_t)r * D);
    dst[lane] = src[lane];
    if (lane == 0) out[(size_t)T_TOTAL * D + r] = (float)k;
}

extern "C" void kernel_launch(void* const* d_in, const int* in_sizes, int n_in,
                              void* d_out, int out_size, void* d_ws, size_t ws_size,
                              hipStream_t stream) {
    const float* seq   = (const float*)d_in[0];   // [T, D] f32
    const float* vocab = (const float*)d_in[1];   // [K, D] f32
    float* out = (float*)d_out;

    float* hv2 = (float*)d_ws;                               // K floats
    int*   idx = (int*)((char*)d_ws + K * sizeof(float));    // T ints

    float2*   partial = (float2*)d_out;                      // 4 MB at head
    _Float16* bhi = (_Float16*)(out + PARTIAL_F);            // 4 MB
    _Float16* blo = bhi + BHALVES;                           // 4 MB
    // all scratch inside d_out's 33.7 MB quantized region; consumed before gather overwrites

    hipLaunchKernelGGL(hv2_kernel,    dim3(K / 4),           dim3(256), 0, stream, vocab, hv2);
    hipLaunchKernelGGL(bsplit_kernel, dim3(NCT),             dim3(256), 0, stream, vocab, bhi, blo);
    hipLaunchKernelGGL(argmin_kernel, dim3(NQB * KSPLIT),    dim3(256), 0, stream,
                       seq, bhi, blo, hv2, partial);
    hipLaunchKernelGGL(reduce_kernel, dim3(T_TOTAL / 256),   dim3(256), 0, stream, partial, idx);
    hipLaunchKernelGGL(gather_kernel, dim3(T_TOTAL / 4),     dim3(256), 0, stream, vocab, idx, out);
}

// Round 13
// 434.152 us; speedup vs baseline: 5.0670x; 1.0271x over previous
//
#include <hip/hip_runtime.h>

// Problem constants: N=512, BS=64, DIM=256, SIZE=8192
#define T_TOTAL 32768   // N*BS queries
#define D       256
#define K       8192
#define BQ      64      // queries per block tile (4 row-tiles of 16) — shared by all 4 waves
#define KSPLIT  4
#define KSLICE  (K / KSPLIT)
#define NSLICE  (KSPLIT * 4)        // (slice, wn) pairs write disjoint partial slices
#define NCT     (K / 16)            // 512 code-tiles
#define KT_STRIDE (NCT * 64 * 8)    // halves per kt plane = 262144
#define NQB     (T_TOTAL / BQ)      // 512 query-blocks

typedef _Float16 half4f  __attribute__((ext_vector_type(4)));
typedef _Float16 half8f  __attribute__((ext_vector_type(8)));
typedef float    floatx4 __attribute__((ext_vector_type(4)));

// d_out scratch: Bhi/Blo after the first PARTIAL_F floats. If ws is big enough,
// partial lives in ws (enables fused reduce+gather); else at d_out head (R12 path).
#define PARTIAL_F 1048576
#define BHALVES   2097152   // halves per B array (8*512*64*8)

__device__ __forceinline__ _Float16 hi16(float x) { return (_Float16)x; }
__device__ __forceinline__ _Float16 lo16(float x, _Float16 h) { return (_Float16)(x - (float)h); }
__device__ __forceinline__ void split4(float4 v, half4f& h, half4f& l) {
    _Float16 hx = hi16(v.x), hy = hi16(v.y), hz = hi16(v.z), hw = hi16(v.w);
    h = (half4f){hx, hy, hz, hw};
    l = (half4f){lo16(v.x, hx), lo16(v.y, hy), lo16(v.z, hz), lo16(v.w, hw)};
}

// ---- kernel 1: fused vocab prep: hv2 (fp32-exact) + fp16 hi/lo fragment-order split ----
// 512 blocks, one 16-code tile each. Wave w handles codes 4w..4w+3 (lane = k4 along D).
__global__ void prep_kernel(const float* __restrict__ vocab,
                            _Float16* __restrict__ bhi, _Float16* __restrict__ blo,
                            float* __restrict__ hv2) {
    const int ct = blockIdx.x;
    const int t  = threadIdx.x;
    const int k4 = t & 63;               // float4 index along D
    const int w  = t >> 6;
    const float4* voc4 = (const float4*)vocab;
    const int kt = k4 >> 3, kg = (k4 >> 1) & 3, h = k4 & 1;
    float ss[4];
    #pragma unroll
    for (int ci = 0; ci < 4; ++ci) {
        int cc = w * 4 + ci;             // code within tile
        float4 v = voc4[(size_t)(ct * 16 + cc) * (D / 4) + k4];
        half4f hh, ll;
        split4(v, hh, ll);
        size_t off = (((size_t)kt * NCT + ct) * 64 + (cc + 16 * kg)) * 8 + h * 4;
        *(half4f*)&bhi[off] = hh;
        *(half4f*)&blo[off] = ll;
        ss[ci] = v.x * v.x + v.y * v.y + v.z * v.z + v.w * v.w;
    }
    #pragma unroll
    for (int ci = 0; ci < 4; ++ci) {
        float s = ss[ci];
        #pragma unroll
        for (int off = 32; off; off >>= 1) s += __shfl_down(s, off, 64);
        if ((t & 63) == 0) hv2[ct * 16 + w * 4 + ci] = 0.5f * s;
    }
}

// -------- kernel 2: MFMA argmin; 3-term split; depth-1 pipeline on BOTH A and B --------
// block 256 = 4 waves; wave wn 0..3 covers a code quadrant; all waves share 64 A rows.
// grid 2048 flattened; XCD swizzle locks one K-slice per XCD (B slice 2 MB < 4 MB L2).
// kt2 loop rolled (unroll 1): bounded hoist window (R8/R9 anti-spill lesson).
// Ping-pong on B (global, R12-proven) AND on A (LDS) to hide both latencies (R12 lesson).
__launch_bounds__(256, 2)
__global__ void argmin_kernel(const float* __restrict__ seq,
                              const _Float16* __restrict__ bhi,
                              const _Float16* __restrict__ blo,
                              const float* __restrict__ hv2,
                              float2* __restrict__ partial) {
    // A LDS in fragment order [rt 0..3][kt 0..7][flane 0..63][8], XOR-swizzled by kt<<3
    __shared__ _Float16 AhL[4 * 8 * 64 * 8];   // 32 KB
    __shared__ _Float16 AlL[4 * 8 * 64 * 8];   // 32 KB

    const int t    = threadIdx.x;
    const int lane = t & 63;
    const int wn   = t >> 6;            // code quadrant 0..3
    const int bi   = blockIdx.x;
    const int slice = (bi & 7) >> 1;    // 0..3  (XCD-locked K-slice)
    const int qb    = (bi >> 3) * 2 + (bi & 1);  // 0..511
    const int q0   = qb * BQ;
    const int k0   = slice * KSLICE;

    const float4* seq4 = (const float4*)seq;

    // ---- prologue: split A (64 rows x 256 dims) into fragment-order LDS, once ----
    #pragma unroll
    for (int i = 0; i < 16; ++i) {
        int f   = t + 256 * i;          // 0..4095 float4s
        int row = f >> 6;               // 0..63
        int d4  = f & 63;               // float4 along D
        float4 v = seq4[(size_t)(q0 + row) * (D / 4) + d4];
        half4f h, l;
        split4(v, h, l);
        int kt = d4 >> 3, kg = (d4 >> 1) & 3, hh = d4 & 1;
        int off = (((((row >> 4) * 8 + kt) * 64) + ((row & 15) + 16 * kg)) * 8 + hh * 4)
                  ^ (kt << 3);          // swizzle: write conflicts 32-way -> 4-way
        *(half4f*)&AhL[off] = h;
        *(half4f*)&AlL[off] = l;
    }
    __syncthreads();   // the ONLY barrier

    float best[16];
    int   bidx[16];
    #pragma unroll
    for (int b = 0; b < 16; ++b) { best[b] = 3.4e38f; bidx[b] = 0; }

    const _Float16* bh_l = bhi + (size_t)lane * 8;
    const _Float16* bl_l = blo + (size_t)lane * 8;

    for (int c0i = 0; c0i < KSLICE / 256; ++c0i) {   // 8 c0 tiles of 256 codes
        const int c0  = k0 + c0i * 256;
        const int ct0 = (c0 >> 4) + wn * 4;          // this wave's 4 code-tiles
        const size_t cb = (size_t)ct0 * 512;

        floatx4 acc[4][4];
        #pragma unroll
        for (int mi = 0; mi < 4; ++mi)
            #pragma unroll
            for (int nj = 0; nj < 4; ++nj) acc[mi][nj] = (floatx4){0.f, 0.f, 0.f, 0.f};

        // ping-pong buffers: B (global) and A (LDS)
        half8f bh0[4], bl0[4], bh1[4], bl1[4];
        half8f ah0[4], al0[4], ah1[4], al1[4];
        #pragma unroll
        for (int nj = 0; nj < 4; ++nj) {          // preload kt=0
            bh0[nj] = *(const half8f*)&bh_l[cb + nj * 512];
            bl0[nj] = *(const half8f*)&bl_l[cb + nj * 512];
        }
        #pragma unroll
        for (int mi = 0; mi < 4; ++mi) {
            const int ao = ((mi * 8) * 64 + lane) * 8;   // kt=0: swizzle term is 0
            ah0[mi] = *(const half8f*)&AhL[ao];
            al0[mi] = *(const half8f*)&AlL[ao];
        }

        #pragma unroll 1   // REAL loop: bounded hoist window (anti-spill)
        for (int kt2 = 0; kt2 < 4; ++kt2) {
            const int kt = kt2 * 2;
            // prefetch kt+1: B -> buf1, A -> areg1 (both overlap kt's MFMA burst)
            {
                const size_t kb = (size_t)(kt + 1) * KT_STRIDE + cb;
                #pragma unroll
                for (int nj = 0; nj < 4; ++nj) {
                    bh1[nj] = *(const half8f*)&bh_l[kb + nj * 512];
                    bl1[nj] = *(const half8f*)&bl_l[kb + nj * 512];
                }
                #pragma unroll
                for (int mi = 0; mi < 4; ++mi) {
                    const int ao = (((mi * 8 + kt + 1) * 64 + lane) * 8) ^ ((kt + 1) << 3);
                    ah1[mi] = *(const half8f*)&AhL[ao];
                    al1[mi] = *(const half8f*)&AlL[ao];
                }
            }
            // MFMA kt with areg0/buf0 (3-term Markidis: ll dropped, err ~2e-6 << gaps)
            #pragma unroll
            for (int nj = 0; nj < 4; ++nj)
                #pragma unroll
                for (int mi = 0; mi < 4; ++mi) {
                    floatx4 a = acc[mi][nj];
                    a = __builtin_amdgcn_mfma_f32_16x16x32_f16(al0[mi], bh0[nj], a, 0, 0, 0);
                    a = __builtin_amdgcn_mfma_f32_16x16x32_f16(ah0[mi], bl0[nj], a, 0, 0, 0);
                    a = __builtin_amdgcn_mfma_f32_16x16x32_f16(ah0[mi], bh0[nj], a, 0, 0, 0);
                    acc[mi][nj] = a;
                }
            // prefetch kt+2 into buf0/areg0 (uniform branch; skipped on last lap)
            if (kt2 < 3) {
                const size_t kb = (size_t)(kt + 2) * KT_STRIDE + cb;
                #pragma unroll
                for (int nj = 0; nj < 4; ++nj) {
                    bh0[nj] = *(const half8f*)&bh_l[kb + nj * 512];
                    bl0[nj] = *(const half8f*)&bl_l[kb + nj * 512];
                }
                #pragma unroll
                for (int mi = 0; mi < 4; ++mi) {
                    const int ao = (((mi * 8 + kt + 2) * 64 + lane) * 8) ^ ((kt + 2) << 3);
                    ah0[mi] = *(const half8f*)&AhL[ao];
                    al0[mi] = *(const half8f*)&AlL[ao];
                }
            }
            // MFMA kt+1 with areg1/buf1
            #pragma unroll
            for (int nj = 0; nj < 4; ++nj)
                #pragma unroll
                for (int mi = 0; mi < 4; ++mi) {
                    floatx4 a = acc[mi][nj];
                    a = __builtin_amdgcn_mfma_f32_16x16x32_f16(al1[mi], bh1[nj], a, 0, 0, 0);
                    a = __builtin_amdgcn_mfma_f32_16x16x32_f16(ah1[mi], bl1[nj], a, 0, 0, 0);
                    a = __builtin_amdgcn_mfma_f32_16x16x32_f16(ah1[mi], bh1[nj], a, 0, 0, 0);
                    acc[mi][nj] = a;
                }
        }

        // epilogue: s = 0.5*|v|^2 - dot; running first-argmin (ascending c per lane).
        // C/D layout: col = lane&15, row = (lane>>4)*4 + reg
        #pragma unroll
        for (int nj = 0; nj < 4; ++nj) {
            int c = c0 + (wn * 4 + nj) * 16 + (lane & 15);
            float hv = hv2[c];
            #pragma unroll
            for (int mi = 0; mi < 4; ++mi)
                #pragma unroll
                for (int r = 0; r < 4; ++r) {
                    float s = hv - acc[mi][nj][r];
                    int b = mi * 4 + r;
                    if (s < best[b]) { best[b] = s; bidx[b] = c; }
                }
        }
    }

    // reduce across the 16 col-lanes (same rows, 16 different cols)
    #pragma unroll
    for (int off = 1; off < 16; off <<= 1) {
        #pragma unroll
        for (int b = 0; b < 16; ++b) {
            float ob = __shfl_xor(best[b], off, 64);
            int   oi = __shfl_xor(bidx[b], off, 64);
            if (ob < best[b] || (ob == best[b] && oi < bidx[b])) {
                best[b] = ob; bidx[b] = oi;
            }
        }
    }
    if ((lane & 15) == 0) {
        const size_t sl = (size_t)(slice * 4 + wn) * T_TOTAL;  // disjoint per (slice, wn)
        #pragma unroll
        for (int mi = 0; mi < 4; ++mi)
            #pragma unroll
            for (int r = 0; r < 4; ++r) {
                int q = q0 + mi * 16 + (lane >> 4) * 4 + r;
                partial[sl + q] = make_float2(best[mi * 4 + r], (float)bidx[mi * 4 + r]);
            }
    }
}

// ---- kernel 3a (fused, needs partial in ws): fold 16 slices + gather, wave per row ----
__global__ void redgather_kernel(const float* __restrict__ vocab,
                                 const float2* __restrict__ partial,
                                 float* __restrict__ out) {
    int r    = blockIdx.x * 4 + (threadIdx.x >> 6);
    int lane = threadIdx.x & 63;
    float bm = 3.4e38f;
    int   bi = 0x7fffffff;
    if (lane < 16) {
        float2 p = partial[(size_t)lane * T_TOTAL + r];
        bm = p.x; bi = (int)p.y;
    }
    #pragma unroll
    for (int off = 1; off < 16; off <<= 1) {   // xor<16 stays within the 16-lane group
        float ob = __shfl_xor(bm, off, 64);
        int   oi = __shfl_xor(bi, off, 64);
        if (ob < bm || (ob == bm && oi < bi)) { bm = ob; bi = oi; }
    }
    int k = __shfl(bi, 0, 64);                 // lanes 0-15 hold the true min; take lane 0
    const float4* src = (const float4*)(vocab + (size_t)k * D);
    float4*       dst = (float4*)(out + (size_t)r * D);
    dst[lane] = src[lane];
    if (lane == 0) out[(size_t)T_TOTAL * D + r] = (float)k;
}

// ---- kernel 3b/4b (fallback path, partial at d_out head): separate reduce + gather ----
__global__ void reduce_kernel(const float2* __restrict__ partial, int* __restrict__ idx) {
    int q = blockIdx.x * 256 + threadIdx.x;
    float bm = 3.4e38f;
    int   bi = 0x7fffffff;
    #pragma unroll
    for (int s = 0; s < NSLICE; ++s) {
        float2 p = partial[(size_t)s * T_TOTAL + q];
        int pi = (int)p.y;
        if (p.x < bm || (p.x == bm && pi < bi)) { bm = p.x; bi = pi; }
    }
    idx[q] = bi;
}

__global__ void gather_kernel(const float* __restrict__ vocab,
                              const int* __restrict__ idx,
                              float* __restrict__ out) {
    int r    = blockIdx.x * 4 + (threadIdx.x >> 6);
    int lane = threadIdx.x & 63;
    int k = idx[r];
    const float4* src = (const float4*)(vocab + (size_t)k * D);
    float4*       dst = (float4*)(out + (size_t)r * D);
    dst[lane] = src[lane];
    if (lane == 0) out[(size_t)T_TOTAL * D + r] = (float)k;
}

extern "C" void kernel_launch(void* const* d_in, const int* in_sizes, int n_in,
                              void* d_out, int out_size, void* d_ws, size_t ws_size,
                              hipStream_t stream) {
    const float* seq   = (const float*)d_in[0];   // [T, D] f32
    const float* vocab = (const float*)d_in[1];   // [K, D] f32
    float* out = (float*)d_out;

    float* hv2 = (float*)d_ws;                               // K floats
    _Float16* bhi = (_Float16*)(out + PARTIAL_F);            // 4 MB (d_out scratch)
    _Float16* blo = bhi + BHALVES;                           // 4 MB

    // partial placement: ws if it fits (enables fused reduce+gather — no cross-kernel
    // race since gather never writes ws), else d_out head (R12 2-kernel path).
    const size_t need_ws = (size_t)(K + 2 * NSLICE * T_TOTAL) * sizeof(float) + 256;
    const bool fused = ws_size >= need_ws;

    hipLaunchKernelGGL(prep_kernel, dim3(NCT), dim3(256), 0, stream, vocab, bhi, blo, hv2);

    if (fused) {
        float2* partial = (float2*)(hv2 + K);                // in ws
        hipLaunchKernelGGL(argmin_kernel,    dim3(NQB * KSPLIT), dim3(256), 0, stream,
                           seq, bhi, blo, hv2, partial);
        hipLaunchKernelGGL(redgather_kernel, dim3(T_TOTAL / 4),  dim3(256), 0, stream,
                           vocab, partial, out);
    } else {
        float2* partial = (float2*)d_out;                    // at d_out head
        int* idx = (int*)(hv2 + K);                          // T ints in ws
        hipLaunchKernelGGL(argmin_kernel, dim3(NQB * KSPLIT), dim3(256), 0, stream,
                           seq, bhi, blo, hv2, partial);
        hipLaunchKernelGGL(reduce_kernel, dim3(T_TOTAL / 256), dim3(256), 0, stream, partial, idx);
        hipLaunchKernelGGL(gather_kernel, dim3(T_TOTAL / 4),   dim3(256), 0, stream, vocab, idx, out);
    }
}